// Round 3
// baseline (237.861 us; speedup 1.0000x reference)
//
#include <hip/hip_runtime.h>

#define DD 4096
#define HH 8192
#define NSPLIT 128

enum Stage { S_X0 = 0, S_TANH, S_BIASOUT, S_PMUL, S_COPY, S_S2 };

__device__ inline unsigned short f2bf(float f) {
    unsigned int u = __float_as_uint(f);
    u += 0x7FFFu + ((u >> 16) & 1u);          // round-to-nearest-even
    return (unsigned short)(u >> 16);
}

// ---------------- fp32 GEMV stage (G1, G2) with fused bf16 conversion ----------------
// Pout[s][n] = sum_{k in slice s} x[k] * W[k][n]; also writes Wb (bf16 copy of W rows < convRows).
template <int STAGE, int KS, int SPREV, int KPREV, int NTOT, int CPT>
__global__ __launch_bounds__(256) void gemv_f32(
    const float* __restrict__ W, const float* __restrict__ Pprev,
    float* __restrict__ Pout, unsigned short* __restrict__ Wb, int convRows,
    const float* __restrict__ h, const float* __restrict__ c,
    const float* __restrict__ b1,
    float* __restrict__ s0g, float* __restrict__ t0g)
{
    constexpr int GROUPS = 256 / KS;
    __shared__ float xs[KS];
    __shared__ float part[GROUPS][KS];
    const int tid = threadIdx.x;
    const int k0 = blockIdx.y * KS;

    if constexpr (STAGE == S_X0) {
        if (tid < KS) {
            int k = k0 + tid;
            xs[tid] = (k < DD) ? h[k] : c[k - DD];
        }
    } else { // S_TANH
        const int g = tid / KS;
        const int j = tid % KS;
        float acc = 0.f;
        for (int s = g; s < SPREV; s += GROUPS)
            acc += Pprev[(size_t)s * KPREV + k0 + j];
        part[g][j] = acc;
        __syncthreads();
        if (tid < KS) {
            const int k = k0 + tid;
            float tot = 0.f;
#pragma unroll
            for (int g2 = 0; g2 < GROUPS; ++g2) tot += part[g2][tid];
            float s = tanhf(tot + b1[k]);
            xs[tid] = s;
            if (blockIdx.x == 0) { s0g[k] = s; t0g[k] = 1.f - s * s; }
        }
    }
    __syncthreads();

    const bool doConv = (k0 < convRows);

    if constexpr (CPT == 4) {
        const int ncol = blockIdx.x * 1024 + tid * 4;
        const float* Wp = W + (size_t)k0 * NTOT + ncol;
        float ax = 0.f, ay = 0.f, az = 0.f, aw = 0.f;
#pragma unroll 4
        for (int k = 0; k < KS; ++k) {
            float xv = xs[k];
            float4 w = *reinterpret_cast<const float4*>(Wp + (size_t)k * NTOT);
            ax = fmaf(xv, w.x, ax);
            ay = fmaf(xv, w.y, ay);
            az = fmaf(xv, w.z, az);
            aw = fmaf(xv, w.w, aw);
            if (doConv) {
                ushort4 o;
                o.x = f2bf(w.x); o.y = f2bf(w.y); o.z = f2bf(w.z); o.w = f2bf(w.w);
                *reinterpret_cast<ushort4*>(Wb + (size_t)(k0 + k) * NTOT + ncol) = o;
            }
        }
        *reinterpret_cast<float4*>(Pout + (size_t)blockIdx.y * NTOT + ncol) =
            make_float4(ax, ay, az, aw);
    } else { // CPT == 2
        const int ncol = blockIdx.x * 512 + tid * 2;
        const float* Wp = W + (size_t)k0 * NTOT + ncol;
        float ax = 0.f, ay = 0.f;
#pragma unroll 4
        for (int k = 0; k < KS; ++k) {
            float xv = xs[k];
            float2 w = *reinterpret_cast<const float2*>(Wp + (size_t)k * NTOT);
            ax = fmaf(xv, w.x, ax);
            ay = fmaf(xv, w.y, ay);
            if (doConv) {
                ushort2 o;
                o.x = f2bf(w.x); o.y = f2bf(w.y);
                *reinterpret_cast<ushort2*>(Wb + (size_t)(k0 + k) * NTOT + ncol) = o;
            }
        }
        *reinterpret_cast<float2*>(Pout + (size_t)blockIdx.y * NTOT + ncol) =
            make_float2(ax, ay);
    }
}

// ---------------- bf16 GEMV stage (G3..G6) ----------------
// Reads bf16 weights (L3-resident), fp32 x built in prologue. CPT=4 (8B loads).
template <int STAGE, int KS, int SPREV, int KPREV, int NTOT>
__global__ __launch_bounds__(256) void gemv_b16(
    const unsigned short* __restrict__ Wb, const float* __restrict__ Pprev,
    float* __restrict__ Pout,
    const float* __restrict__ b2, const float* __restrict__ s0g,
    const float* __restrict__ t0g, float* __restrict__ a1g,
    float* __restrict__ outv)
{
    constexpr int GROUPS = 256 / KS;
    __shared__ float xs[KS];
    __shared__ float part[GROUPS][KS];
    const int tid = threadIdx.x;
    const int k0 = blockIdx.y * KS;

    {
        const int g = tid / KS;
        const int j = tid % KS;
        float acc = 0.f;
        for (int s = g; s < SPREV; s += GROUPS)
            acc += Pprev[(size_t)s * KPREV + k0 + j];
        part[g][j] = acc;
        __syncthreads();
        if (tid < KS) {
            const int k = k0 + tid;
            float tot = 0.f;
#pragma unroll
            for (int g2 = 0; g2 < GROUPS; ++g2) tot += part[g2][tid];
            float xv;
            if constexpr (STAGE == S_BIASOUT) {
                xv = tot + b2[k];
                if (blockIdx.x == 0) outv[k] = xv;
            } else if constexpr (STAGE == S_PMUL) {
                xv = t0g[k] * tot;
                if (blockIdx.x == 0) a1g[k] = tot;
            } else if constexpr (STAGE == S_COPY) {
                xv = tot;
            } else { // S_S2
                float a1v = a1g[k];
                xv = t0g[k] * (tot - s0g[k] * a1v * a1v);
            }
            xs[tid] = xv;
        }
    }
    __syncthreads();

    const int ncol = blockIdx.x * 1024 + tid * 4;
    const unsigned short* Wp = Wb + (size_t)k0 * NTOT + ncol;
    float ax = 0.f, ay = 0.f, az = 0.f, aw = 0.f;
#pragma unroll 8
    for (int k = 0; k < KS; ++k) {
        float xv = xs[k];
        uint2 w = *reinterpret_cast<const uint2*>(Wp + (size_t)k * NTOT);
        float w0 = __uint_as_float(w.x << 16);
        float w1 = __uint_as_float(w.x & 0xFFFF0000u);
        float w2 = __uint_as_float(w.y << 16);
        float w3 = __uint_as_float(w.y & 0xFFFF0000u);
        ax = fmaf(xv, w0, ax);
        ay = fmaf(xv, w1, ay);
        az = fmaf(xv, w2, az);
        aw = fmaf(xv, w3, aw);
    }
    *reinterpret_cast<float4*>(Pout + (size_t)blockIdx.y * NTOT + ncol) =
        make_float4(ax, ay, az, aw);
}

// C2[n] = sum_s P6[s][n]
__global__ __launch_bounds__(256) void reduce_C2(const float* __restrict__ P6,
                                                 float* __restrict__ C2) {
    int n = blockIdx.x * 256 + threadIdx.x;
    float acc = 0.f;
#pragma unroll 8
    for (int s = 0; s < NSPLIT; ++s) acc += P6[(size_t)s * DD + n];
    C2[n] = acc;
}

__global__ __launch_bounds__(256) void reduce_meansq(const float* __restrict__ C2v,
                                                     float* __restrict__ dout) {
    float s = 0.f;
    for (int i = threadIdx.x; i < DD; i += 256) {
        float v = C2v[i];
        s = fmaf(v, v, s);
    }
    for (int off = 32; off; off >>= 1) s += __shfl_down(s, off);
    __shared__ float ls[4];
    int wid = threadIdx.x >> 6;
    if ((threadIdx.x & 63) == 0) ls[wid] = s;
    __syncthreads();
    if (threadIdx.x == 0) dout[DD] = (ls[0] + ls[1] + ls[2] + ls[3]) / (float)DD;
}

extern "C" void kernel_launch(void* const* d_in, const int* in_sizes, int n_in,
                              void* d_out, int out_size, void* d_ws, size_t ws_size,
                              hipStream_t stream) {
    const float* h  = (const float*)d_in[0];
    const float* c  = (const float*)d_in[3];
    const float* W1 = (const float*)d_in[4];   // (DD+CC) x HH row-major
    const float* b1 = (const float*)d_in[5];
    const float* W2 = (const float*)d_in[6];   // HH x DD row-major
    const float* b2 = (const float*)d_in[7];
    float* out = (float*)d_out;                // [0..4095]=dydt, [4096]=mean(drdt^2)
    float* ws = (float*)d_ws;

    // workspace layout (floats)
    float* P1 = ws;                 // 128 x 8192
    float* P2 = P1 + 1048576;       // 128 x 4096
    float* P3 = P2 + 524288;        // 128 x 8192
    float* P4 = P3 + 1048576;       // 128 x 4096
    float* P5 = P4 + 524288;        // 128 x 8192
    float* P6 = P5 + 1048576;       // 128 x 4096
    float* s0 = P6 + 524288;        // 8192
    float* t0 = s0 + 8192;          // 8192
    float* a1 = t0 + 8192;          // 8192
    float* C2 = a1 + 8192;          // 4096
    unsigned short* W1b = (unsigned short*)(C2 + 4096);      // 4096 x 8192 bf16 (64MB)
    unsigned short* W2b = W1b + (size_t)DD * HH;             // 8192 x 4096 bf16 (64MB)

    // G1: a0 partials = concat(h,c) @ W1  (K=8192, N=8192); converts W1[:4096] -> W1b
    gemv_f32<S_X0, 64, 1, 1, HH, 4><<<dim3(8, NSPLIT), 256, 0, stream>>>(
        W1, nullptr, P1, W1b, DD, h, c, b1, s0, t0);
    // G2: s0 = tanh(a0+b1); Fr partials = s0 @ W2 (K=8192, N=4096); converts W2 -> W2b
    gemv_f32<S_TANH, 64, NSPLIT, HH, DD, 2><<<dim3(8, NSPLIT), 256, 0, stream>>>(
        W2, P1, P2, W2b, HH, h, c, b1, s0, t0);
    // G3: Ff = Fr+b2 -> out; a1 partials = Ff @ W1b (K=4096, N=8192)
    gemv_b16<S_BIASOUT, 32, NSPLIT, DD, HH><<<dim3(8, NSPLIT), 256, 0, stream>>>(
        W1b, P2, P3, b2, s0, t0, a1, out);
    // G4: p1 = t0*a1; v partials = p1 @ W2b (K=8192, N=4096)
    gemv_b16<S_PMUL, 64, NSPLIT, HH, DD><<<dim3(4, NSPLIT), 256, 0, stream>>>(
        W2b, P3, P4, b2, s0, t0, a1, out);
    // G5: a2 partials = v @ W1b (K=4096, N=8192)
    gemv_b16<S_COPY, 32, NSPLIT, DD, HH><<<dim3(8, NSPLIT), 256, 0, stream>>>(
        W1b, P4, P5, b2, s0, t0, a1, out);
    // G6: s2 = t0*(a2 - s0*a1^2); C2 partials = s2 @ W2b (K=8192, N=4096)
    gemv_b16<S_S2, 64, NSPLIT, HH, DD><<<dim3(4, NSPLIT), 256, 0, stream>>>(
        W2b, P5, P6, b2, s0, t0, a1, out);
    // C2 = reduce(P6); out[4096] = mean(C2^2)
    reduce_C2<<<16, 256, 0, stream>>>(P6, C2);
    reduce_meansq<<<1, 256, 0, stream>>>(C2, out);
}

// Round 5
// 223.414 us; speedup vs baseline: 1.0647x; 1.0647x over previous
//
#include <hip/hip_runtime.h>

#define DD 4096
#define HH 8192

enum Stage { S_X0 = 0, S_TANH, S_BIASOUT, S_PMUL, S_COPY, S_S2 };

typedef float vfloat4 __attribute__((ext_vector_type(4)));

__device__ inline unsigned short f2bf(float f) {
    unsigned int u = __float_as_uint(f);
    u += 0x7FFFu + ((u >> 16) & 1u);          // round-to-nearest-even
    return (unsigned short)(u >> 16);
}

__device__ inline vfloat4 ldnt4(const float* p) {
    return __builtin_nontemporal_load(reinterpret_cast<const vfloat4*>(p));
}

// ---------------- fp32 GEMV stage (G1, G2), 16B/lane, fused bf16 conversion --------
// Pout[s][n] = sum_{k in slice s} x[k] * W[k][n]; writes Wb for rows < convRows.
template <int STAGE, int KS, int SPREV, int KPREV, int NTOT>
__global__ __launch_bounds__(256) void gemv_f32(
    const float* __restrict__ W, const float* __restrict__ Pprev,
    float* __restrict__ Pout, unsigned short* __restrict__ Wb, int convRows,
    const float* __restrict__ h, const float* __restrict__ c,
    const float* __restrict__ b1,
    float* __restrict__ s0g, float* __restrict__ t0g)
{
    constexpr int GROUPS = 256 / KS;
    __shared__ float xs[KS];
    __shared__ float part[GROUPS][KS];
    const int tid = threadIdx.x;
    const int k0 = blockIdx.y * KS;

    if constexpr (STAGE == S_X0) {
        if (tid < KS) {
            int k = k0 + tid;
            xs[tid] = (k < DD) ? h[k] : c[k - DD];
        }
    } else { // S_TANH
        const int g = tid / KS;
        const int j = tid % KS;
        float acc = 0.f;
        for (int s = g; s < SPREV; s += GROUPS)
            acc += Pprev[(size_t)s * KPREV + k0 + j];
        part[g][j] = acc;
        __syncthreads();
        if (tid < KS) {
            const int k = k0 + tid;
            float tot = 0.f;
#pragma unroll
            for (int g2 = 0; g2 < GROUPS; ++g2) tot += part[g2][tid];
            float s = tanhf(tot + b1[k]);
            xs[tid] = s;
            if (blockIdx.x == 0) { s0g[k] = s; t0g[k] = 1.f - s * s; }
        }
    }
    __syncthreads();

    const bool doConv = (k0 < convRows);
    const int ncol = blockIdx.x * 1024 + tid * 4;
    const float* Wp = W + (size_t)k0 * NTOT + ncol;
    float ax = 0.f, ay = 0.f, az = 0.f, aw = 0.f;
#pragma unroll 4
    for (int k = 0; k < KS; ++k) {
        float xv = xs[k];
        vfloat4 w = ldnt4(Wp + (size_t)k * NTOT);
        ax = fmaf(xv, w.x, ax);
        ay = fmaf(xv, w.y, ay);
        az = fmaf(xv, w.z, az);
        aw = fmaf(xv, w.w, aw);
        if (doConv) {
            ushort4 o;
            o.x = f2bf(w.x); o.y = f2bf(w.y); o.z = f2bf(w.z); o.w = f2bf(w.w);
            *reinterpret_cast<ushort4*>(Wb + (size_t)(k0 + k) * NTOT + ncol) = o;
        }
    }
    *reinterpret_cast<float4*>(Pout + (size_t)blockIdx.y * NTOT + ncol) =
        make_float4(ax, ay, az, aw);
}

// ---------------- bf16 GEMV stage (G3..G6), uint4 = 8 bf16/lane ----------------
template <int STAGE, int KS, int SPREV, int KPREV, int NTOT>
__global__ __launch_bounds__(256) void gemv_b16(
    const unsigned short* __restrict__ Wb, const float* __restrict__ Pprev,
    float* __restrict__ Pout,
    const float* __restrict__ b2, const float* __restrict__ s0g,
    const float* __restrict__ t0g, float* __restrict__ a1g,
    float* __restrict__ outv)
{
    constexpr int GROUPS = 256 / KS;
    __shared__ float xs[KS];
    __shared__ float part[GROUPS][KS];
    const int tid = threadIdx.x;
    const int k0 = blockIdx.y * KS;

    {
        const int g = tid / KS;
        const int j = tid % KS;
        float acc = 0.f;
        for (int s = g; s < SPREV; s += GROUPS)
            acc += Pprev[(size_t)s * KPREV + k0 + j];
        part[g][j] = acc;
        __syncthreads();
        if (tid < KS) {
            const int k = k0 + tid;
            float tot = 0.f;
#pragma unroll
            for (int g2 = 0; g2 < GROUPS; ++g2) tot += part[g2][tid];
            float xv;
            if constexpr (STAGE == S_BIASOUT) {
                xv = tot + b2[k];
                if (blockIdx.x == 0) outv[k] = xv;
            } else if constexpr (STAGE == S_PMUL) {
                xv = t0g[k] * tot;
                if (blockIdx.x == 0) a1g[k] = tot;
            } else if constexpr (STAGE == S_COPY) {
                xv = tot;
            } else { // S_S2
                float a1v = a1g[k];
                xv = t0g[k] * (tot - s0g[k] * a1v * a1v);
            }
            xs[tid] = xv;
        }
    }
    __syncthreads();

    const int ncol = blockIdx.x * 2048 + tid * 8;
    const unsigned short* Wp = Wb + (size_t)k0 * NTOT + ncol;
    float a0 = 0.f, a1 = 0.f, a2 = 0.f, a3 = 0.f;
    float a4 = 0.f, a5 = 0.f, a6 = 0.f, a7 = 0.f;
#pragma unroll 4
    for (int k = 0; k < KS; ++k) {
        float xv = xs[k];
        uint4 w = *reinterpret_cast<const uint4*>(Wp + (size_t)k * NTOT);
        a0 = fmaf(xv, __uint_as_float(w.x << 16), a0);
        a1 = fmaf(xv, __uint_as_float(w.x & 0xFFFF0000u), a1);
        a2 = fmaf(xv, __uint_as_float(w.y << 16), a2);
        a3 = fmaf(xv, __uint_as_float(w.y & 0xFFFF0000u), a3);
        a4 = fmaf(xv, __uint_as_float(w.z << 16), a4);
        a5 = fmaf(xv, __uint_as_float(w.z & 0xFFFF0000u), a5);
        a6 = fmaf(xv, __uint_as_float(w.w << 16), a6);
        a7 = fmaf(xv, __uint_as_float(w.w & 0xFFFF0000u), a7);
    }
    float* op = Pout + (size_t)blockIdx.y * NTOT + ncol;
    *reinterpret_cast<float4*>(op)     = make_float4(a0, a1, a2, a3);
    *reinterpret_cast<float4*>(op + 4) = make_float4(a4, a5, a6, a7);
}

// C2[n] = sum_s P6[s][n]
template <int SPREV>
__global__ __launch_bounds__(256) void reduce_C2(const float* __restrict__ P6,
                                                 float* __restrict__ C2) {
    int n = blockIdx.x * 256 + threadIdx.x;
    float acc = 0.f;
#pragma unroll 8
    for (int s = 0; s < SPREV; ++s) acc += P6[(size_t)s * DD + n];
    C2[n] = acc;
}

__global__ __launch_bounds__(256) void reduce_meansq(const float* __restrict__ C2v,
                                                     float* __restrict__ dout) {
    float s = 0.f;
    for (int i = threadIdx.x; i < DD; i += 256) {
        float v = C2v[i];
        s = fmaf(v, v, s);
    }
    for (int off = 32; off; off >>= 1) s += __shfl_down(s, off);
    __shared__ float ls[4];
    int wid = threadIdx.x >> 6;
    if ((threadIdx.x & 63) == 0) ls[wid] = s;
    __syncthreads();
    if (threadIdx.x == 0) dout[DD] = (ls[0] + ls[1] + ls[2] + ls[3]) / (float)DD;
}

extern "C" void kernel_launch(void* const* d_in, const int* in_sizes, int n_in,
                              void* d_out, int out_size, void* d_ws, size_t ws_size,
                              hipStream_t stream) {
    const float* h  = (const float*)d_in[0];
    const float* c  = (const float*)d_in[3];
    const float* W1 = (const float*)d_in[4];   // (DD+CC) x HH row-major
    const float* b1 = (const float*)d_in[5];
    const float* W2 = (const float*)d_in[6];   // HH x DD row-major
    const float* b2 = (const float*)d_in[7];
    float* out = (float*)d_out;                // [0..4095]=dydt, [4096]=mean(drdt^2)
    float* ws = (float*)d_ws;

    // workspace layout (floats)
    float* P1 = ws;                 // 128 x 8192
    float* P2 = P1 + 1048576;       // 256 x 4096
    float* P3 = P2 + 1048576;       // 256 x 8192
    float* P4 = P3 + 2097152;       // 512 x 4096
    float* P5 = P4 + 2097152;       // 256 x 8192
    float* P6 = P5 + 2097152;       // 512 x 4096
    float* s0 = P6 + 2097152;       // 8192
    float* t0 = s0 + 8192;          // 8192
    float* a1 = t0 + 8192;          // 8192
    float* C2 = a1 + 8192;          // 4096
    unsigned short* W1b = (unsigned short*)(C2 + 4096);   // 4096 x 8192 bf16 (64MB)
    unsigned short* W2b = W1b + (size_t)DD * HH;          // 8192 x 4096 bf16 (64MB)

    // G1: a0 partials = concat(h,c) @ W1 (K=8192,N=8192) fp32; conv W1[:4096]->W1b
    gemv_f32<S_X0, 64, 1, 1, HH><<<dim3(8, 128), 256, 0, stream>>>(
        W1, nullptr, P1, W1b, DD, h, c, b1, s0, t0);
    // G2: s0=tanh(a0+b1); Fr partials = s0 @ W2 (K=8192,N=4096) fp32; conv W2->W2b
    gemv_f32<S_TANH, 32, 128, HH, DD><<<dim3(4, 256), 256, 0, stream>>>(
        W2, P1, P2, W2b, HH, h, c, b1, s0, t0);
    // G3: Ff=Fr+b2 -> out; a1 partials = Ff @ W1b (K=4096,N=8192)
    gemv_b16<S_BIASOUT, 16, 256, DD, HH><<<dim3(4, 256), 256, 0, stream>>>(
        W1b, P2, P3, b2, s0, t0, a1, out);
    // G4: p1=t0*a1; v partials = p1 @ W2b (K=8192,N=4096)
    gemv_b16<S_PMUL, 16, 256, HH, DD><<<dim3(2, 512), 256, 0, stream>>>(
        W2b, P3, P4, b2, s0, t0, a1, out);
    // G5: a2 partials = v @ W1b (K=4096,N=8192)
    gemv_b16<S_COPY, 16, 512, DD, HH><<<dim3(4, 256), 256, 0, stream>>>(
        W1b, P4, P5, b2, s0, t0, a1, out);
    // G6: s2=t0*(a2-s0*a1^2); C2 partials = s2 @ W2b (K=8192,N=4096)
    gemv_b16<S_S2, 16, 256, HH, DD><<<dim3(2, 512), 256, 0, stream>>>(
        W2b, P5, P6, b2, s0, t0, a1, out);
    // C2 = reduce(P6); out[4096] = mean(C2^2)
    reduce_C2<512><<<16, 256, 0, stream>>>(P6, C2);
    reduce_meansq<<<1, 256, 0, stream>>>(C2, out);
}